// Round 1
// baseline (333.872 us; speedup 1.0000x reference)
//
#include <hip/hip_runtime.h>
#include <math.h>

#define NDIM 128
#define AS 33              // per-dim array stride (33 floats)
#define LUT_D (32*AS)      // 1056 floats per array per 32-dim panel
#define TAB_D (NDIM*AS)    // 4224 floats per array (all dims)
#define GRIDX 384
#define LN2F 0.69314718055994530942f

// ---------------- table builder: one thread per dim ----------------
__global__ void rqs_build(const float* __restrict__ sp, float* __restrict__ tab) {
  const int d = blockIdx.x * 64 + threadIdx.x;
  if (d >= NDIM) return;
  const float* pp = sp + d * 97;
  const float offs = (float)log(expm1(1.0 - 1e-4));  // matches np.log(np.expm1(1-MIN_KNOT_SLOPE))

  // widths -> x_pos (array 0)
  {
    float m = -INFINITY;
    for (int i = 0; i < 32; ++i) m = fmaxf(m, pp[i]);
    float s = 0.f;
    for (int i = 0; i < 32; ++i) s += expf(pp[i] - m);
    float c = 0.f;
    tab[0*TAB_D + d*AS] = -5.0f;
    for (int i = 0; i < 32; ++i) {
      float w = (expf(pp[i] - m) / s) * 9.9968f + 1e-4f;  // softmax*(total-K*mbs)+mbs
      c += w;
      tab[0*TAB_D + d*AS + i + 1] = -5.0f + c;
    }
  }
  // heights -> y_pos (array 2)
  {
    float m = -INFINITY;
    for (int i = 0; i < 32; ++i) m = fmaxf(m, pp[32+i]);
    float s = 0.f;
    for (int i = 0; i < 32; ++i) s += expf(pp[32+i] - m);
    float c = 0.f;
    tab[2*TAB_D + d*AS] = -5.0f;
    for (int i = 0; i < 32; ++i) {
      float h = (expf(pp[32+i] - m) / s) * 9.9968f + 1e-4f;
      c += h;
      tab[2*TAB_D + d*AS + i + 1] = -5.0f + c;
    }
  }
  // slopes (array 1): softplus(us+offset)+min_slope, jax logaddexp form
  for (int i = 0; i < 33; ++i) {
    float t = pp[64+i] + offs;
    float sl = fmaxf(t, 0.f) + log1pf(expf(-fabsf(t))) + 1e-4f;
    tab[1*TAB_D + d*AS + i] = sl;
  }
  // derived: inv_bw (3), bh (4), bs (5) -- exact IEEE divisions here
  for (int i = 0; i < 32; ++i) {
    float x0 = tab[0*TAB_D + d*AS + i], x1 = tab[0*TAB_D + d*AS + i + 1];
    float y0 = tab[2*TAB_D + d*AS + i], y1 = tab[2*TAB_D + d*AS + i + 1];
    float bw = x1 - x0, bh = y1 - y0;
    tab[3*TAB_D + d*AS + i] = 1.0f / bw;
    tab[4*TAB_D + d*AS + i] = bh;
    tab[5*TAB_D + d*AS + i] = bh / bw;
  }
  tab[3*TAB_D + d*AS + 32] = 0.f;
  tab[4*TAB_D + d*AS + 32] = 0.f;
  tab[5*TAB_D + d*AS + 32] = 0.f;
}

// ---------------- main kernel: panel of 32 dims per block ----------------
// block = 256 threads = 8 rows x 32 dims; lane<->dim 1:1 so LDS gathers
// spread over all 32 banks and global x/y accesses are 128B/row coalesced.
__global__ __launch_bounds__(256, 6)
void rqs_main(const float* __restrict__ x, const float* __restrict__ tab,
              float* __restrict__ y, float* __restrict__ ld, int ntiles) {
  __shared__ float lut[6*LUT_D];   // 25,344 B -> 6 blocks/CU
  const int tid = threadIdx.x;
  const int p = blockIdx.y;
  for (int a = 0; a < 6; ++a)
    for (int i = tid; i < LUT_D; i += 256)
      lut[a*LUT_D + i] = tab[a*TAB_D + p*LUT_D + i];
  __syncthreads();

  const int dl = tid & 31;
  const int rl = tid >> 5;               // 0..7
  const int d  = p*32 + dl;
  const float* xp = lut + dl*AS;         // x_pos for this dim
  const float x_last  = xp[32];
  const float s_first = lut[1*LUT_D + dl*AS + 0];
  const float s_last  = lut[1*LUT_D + dl*AS + 32];
  const float y_last  = lut[2*LUT_D + dl*AS + 32];
  const float l2_sf = __log2f(s_first);
  const float l2_sl = __log2f(s_last);

  const long long stride = (long long)GRIDX * 8 * NDIM;
  const float* xin  = x  + (long long)(blockIdx.x*8 + rl) * NDIM + d;
  float*       yout = y  + (long long)(blockIdx.x*8 + rl) * NDIM + d;
  float*       ldp  = ld + blockIdx.x*8 + rl;

  for (int t = blockIdx.x; t < ntiles; t += GRIDX) {
    const float v = *xin;

    // branchless binary search: largest lo in [0,31] with xp[lo] <= v
    // (== clip(searchsorted_right(x_pos, v)-1, 0, K-1)); x0 tracked for free
    int lo = 0;
    float x0 = -5.0f;                    // x_pos[0] is exactly RANGE_MIN
    #pragma unroll
    for (int st_ = 16; st_ >= 1; st_ >>= 1) {
      const int cand = lo + st_;
      const float xv = xp[cand];
      const bool le = (xv <= v);
      lo = le ? cand : lo;
      x0 = le ? xv : x0;
    }

    const int base = dl*AS + lo;         // one vaddr, per-array imm offsets
    const float s0  = lut[1*LUT_D + base];
    const float s1  = lut[1*LUT_D + base + 1];
    const float y0  = lut[2*LUT_D + base];
    const float ibw = lut[3*LUT_D + base];
    const float bh  = lut[4*LUT_D + base];
    const float bs  = lut[5*LUT_D + base];

    float z = (v - x0) * ibw;
    z = fminf(fmaxf(z, 0.f), 1.f);
    const float zz    = z*z;
    const float z1mz  = z - zz;
    const float omz   = 1.f - z;
    const float sq1mz = omz*omz;
    const float st2   = fmaf(-2.f, bs, s0 + s1);     // s0+s1-2bs
    const float den   = fmaf(st2, z1mz, bs);
    float r = __builtin_amdgcn_rcpf(den);
    r = r * (2.f - den * r);                          // Newton -> ~0.5 ulp
    float num = bs*zz;
    num = fmaf(s0, z1mz, num);
    num = num * bh;
    float yv = fmaf(num, r, y0);
    float P = s1*zz;
    P = fmaf(bs, z1mz + z1mz, P);
    P = fmaf(s0, sq1mz, P);
    const float bs2 = bs*bs;
    float arg = (bs2 * P) * (r * r);
    float l2v = __log2f(arg);     // logdet = ln2 * log2(bs^2 * P / den^2)

    // out-of-range tails: ~19 of 33.5M elements -> wave-voted rare branch
    const bool below = (v <= -5.0f);
    const bool above = (v >= x_last);
    if (__builtin_expect(__any(below || above), 0)) {
      const float ye = below ? fmaf(v + 5.0f, s_first, -5.0f)
                             : fmaf(v - x_last, s_last, y_last);
      const float le = below ? l2_sf : l2_sl;
      if (below || above) { yv = ye; l2v = le; }
    }
    *yout = yv;

    // per-row logdet: butterfly over the 32 lanes of this row
    float sum = l2v;
    sum += __shfl_xor(sum, 1);
    sum += __shfl_xor(sum, 2);
    sum += __shfl_xor(sum, 4);
    sum += __shfl_xor(sum, 8);
    sum += __shfl_xor(sum, 16);
    if (dl == 0) atomicAdd(ldp, sum * LN2F);

    xin += stride; yout += stride; ldp += GRIDX*8;
  }
}

extern "C" void kernel_launch(void* const* d_in, const int* in_sizes, int n_in,
                              void* d_out, int out_size, void* d_ws, size_t ws_size,
                              hipStream_t stream) {
  const float* x  = (const float*)d_in[0];
  const float* sp = (const float*)d_in[1];
  float* out = (float*)d_out;
  const int n = in_sizes[0] / NDIM;              // 262144
  float* y  = out;
  float* ld = out + (long long)n * NDIM;
  float* tab = (float*)d_ws;                     // needs 6*4224*4 = 101,376 B

  hipMemsetAsync(ld, 0, n * sizeof(float), stream);
  rqs_build<<<dim3(2), dim3(64), 0, stream>>>(sp, tab);
  rqs_main<<<dim3(GRIDX, 4), dim3(256), 0, stream>>>(x, tab, y, ld, n / 8);
}